// Round 2
// baseline (515.773 us; speedup 1.0000x reference)
//
#include <hip/hip_runtime.h>
#include <math.h>

#define NB 256     // batch
#define IC 1152    // input capsules
#define OC 10     // output capsules
#define OU 16     // output units
#define IK 8      // input units

#define S_ISPLIT 48
#define S_IRANGE (IC / S_ISPLIT)   // 24
#define S_ICH 8
#define S_NCH (S_IRANGE / S_ICH)   // 3

// s-pass: block = 256 thr = 64 b-pairs x 4 u-quads; covers 128 b, one o, 24 i.
// grid (10, 2, 48) = 960 blocks. Softmax fused (per-block recompute for its i's).
// Accumulates s[b,o,u] via atomicAdd.
__global__ __launch_bounds__(256) void spass_kernel(
    const float* __restrict__ inp,   // [NB][IC][IK]
    const float* __restrict__ W,     // [IC][OC][OU][IK]
    const float* __restrict__ blog,  // [IC][OC]
    float* __restrict__ s)           // [NB][OC][OU] accum
{
    const int o     = blockIdx.x;
    const int btile = blockIdx.y;          // 0..1
    const int i0    = blockIdx.z * S_IRANGE;
    const int tid   = threadIdx.x;
    const int bp    = tid & 63;            // b-pair base
    const int uq    = tid >> 6;            // u-quad: u = uq*4 + j
    const int bbase = btile * 128;

    __shared__ float c_loc[S_IRANGE];
    __shared__ float inT[S_ICH][IK][129];  // transposed inp tile, 33 KB
    __shared__ float wl[S_ICH][OU * IK];   // W tile, 4 KB

    // fused softmax for this block's i-range (column o only)
    if (tid < S_IRANGE) {
        const float* br = &blog[(size_t)(i0 + tid) * OC];
        float x[OC];
        float m = -1e30f;
#pragma unroll
        for (int oo = 0; oo < OC; ++oo) { x[oo] = br[oo]; m = fmaxf(m, x[oo]); }
        float sum = 0.f;
#pragma unroll
        for (int oo = 0; oo < OC; ++oo) sum += expf(x[oo] - m);
        c_loc[tid] = expf(x[o] - m) / sum;
    }

    float acc[2][4];
#pragma unroll
    for (int bi = 0; bi < 2; ++bi)
#pragma unroll
        for (int j = 0; j < 4; ++j) acc[bi][j] = 0.f;

    for (int ch = 0; ch < S_NCH; ++ch) {
        const int ib = i0 + ch * S_ICH;
        __syncthreads();
        // stage inp[bbase..+127][ib..ib+7][0..7] transposed -> inT[ii][k][b]
#pragma unroll
        for (int j = 0; j < 8; ++j) {
            int q  = j * 256 + tid;      // float4 id, 2048 total
            int bb = q >> 4;             // 0..127
            int f  = q & 15;
            int ii = f >> 1;
            int k4 = (f & 1) * 4;
            float4 g = *(const float4*)&inp[(size_t)(bbase + bb) * (IC * IK) +
                                            (size_t)(ib + ii) * IK + k4];
            inT[ii][k4 + 0][bb] = g.x;
            inT[ii][k4 + 1][bb] = g.y;
            inT[ii][k4 + 2][bb] = g.z;
            inT[ii][k4 + 3][bb] = g.w;
        }
        // stage W[ib..ib+7][o][:][:]
        {
            int ii = tid >> 5, f = tid & 31;
            *(float4*)&wl[ii][f * 4] =
                *(const float4*)&W[((size_t)(ib + ii) * OC + o) * (OU * IK) + f * 4];
        }
        __syncthreads();

#pragma unroll
        for (int ii = 0; ii < S_ICH; ++ii) {
            float x0[IK], x1[IK];
#pragma unroll
            for (int k = 0; k < IK; ++k) {
                x0[k] = inT[ii][k][bp];
                x1[k] = inT[ii][k][bp + 64];
            }
            float cc = c_loc[ch * S_ICH + ii];
#pragma unroll
            for (int j = 0; j < 4; ++j) {
                const float* wr = &wl[ii][(uq * 4 + j) * IK];
                float4 wa = *(const float4*)wr;
                float4 wb = *(const float4*)(wr + 4);
                float d0 = wa.x*x0[0] + wa.y*x0[1] + wa.z*x0[2] + wa.w*x0[3]
                         + wb.x*x0[4] + wb.y*x0[5] + wb.z*x0[6] + wb.w*x0[7];
                float d1 = wa.x*x1[0] + wa.y*x1[1] + wa.z*x1[2] + wa.w*x1[3]
                         + wb.x*x1[4] + wb.y*x1[5] + wb.z*x1[6] + wb.w*x1[7];
                acc[0][j] += cc * d0;
                acc[1][j] += cc * d1;
            }
        }
    }

#pragma unroll
    for (int bi = 0; bi < 2; ++bi)
#pragma unroll
        for (int j = 0; j < 4; ++j)
            atomicAdd(&s[((size_t)(bbase + bp + bi * 64) * OC + o) * OU + uq * 4 + j],
                      acc[bi][j]);
}

// squash: v = s*(|s|^2/((1+|s|^2)sqrt(|s|^2+eps))); also zeroes s for next round.
__global__ __launch_bounds__(256) void squash_kernel(
    float* __restrict__ s, float* __restrict__ vout)
{
    int e = blockIdx.x * 256 + threadIdx.x;   // < 40960, u = e & 15
    float sv = s[e];
    float sq = sv * sv;
    sq += __shfl_xor(sq, 1);
    sq += __shfl_xor(sq, 2);
    sq += __shfl_xor(sq, 4);
    sq += __shfl_xor(sq, 8);
    vout[e] = sv * (sq / ((1.f + sq) * sqrtf(sq + 1e-9f)));
    s[e] = 0.f;
}

#define D_BSPLIT 8
#define D_BRANGE (NB / D_BSPLIT)  // 32
#define D_BCH 8
#define D_NCH (D_BRANGE / D_BCH)  // 4

// delta: blog[i,o] += 1/NB * sum_{b,u} dot8(W[i,o,u,:], inp[b,i,:]) * v[b,o,u]
// block = 256 thr = 128 i x 2 u-halves; one o; 32 b's. grid (10, 9, 8) = 720.
// W held in registers (i fixed per thread for whole block).
__global__ __launch_bounds__(256) void delta_kernel(
    const float* __restrict__ inp,   // [NB][IC][IK]
    const float* __restrict__ W,     // [IC][OC][OU][IK]
    const float* __restrict__ v,     // [NB][OC][OU]
    float* __restrict__ blog)        // [IC][OC] accum
{
    const int o     = blockIdx.x;
    const int itile = blockIdx.y;          // 0..8
    const int b0    = blockIdx.z * D_BRANGE;
    const int tid   = threadIdx.x;
    const int i_loc = tid & 127;
    const int ug    = tid >> 7;            // u-set = ug*8..ug*8+7
    const int i     = itile * 128 + i_loc;

    __shared__ float inT[D_BCH][IK][129];  // 33 KB
    __shared__ float vl[D_BCH * OU];       // 512 B

    float w[8][8];
    {
        const float* wrow = &W[((size_t)i * OC + o) * (OU * IK) + ug * 64];
#pragma unroll
        for (int j = 0; j < 8; ++j) {
            float4 a = *(const float4*)(wrow + j * 8);
            float4 bq = *(const float4*)(wrow + j * 8 + 4);
            w[j][0] = a.x;  w[j][1] = a.y;  w[j][2] = a.z;  w[j][3] = a.w;
            w[j][4] = bq.x; w[j][5] = bq.y; w[j][6] = bq.z; w[j][7] = bq.w;
        }
    }

    float acc = 0.f;
    for (int ch = 0; ch < D_NCH; ++ch) {
        const int bb0 = b0 + ch * D_BCH;
        __syncthreads();
        // stage inp[bb0..+7][itile*128..+127][0..7] transposed -> inT[bb][k][i]
#pragma unroll
        for (int j = 0; j < 8; ++j) {
            int q  = j * 256 + tid;     // float4 id, 2048 total
            int bb = q >> 8;            // 0..7
            int f  = q & 255;
            int ii = f >> 1;            // 0..127
            int k4 = (f & 1) * 4;
            float4 g = *(const float4*)&inp[(size_t)(bb0 + bb) * (IC * IK) +
                                            (size_t)(itile * 128 + ii) * IK + k4];
            inT[bb][k4 + 0][ii] = g.x;
            inT[bb][k4 + 1][ii] = g.y;
            inT[bb][k4 + 2][ii] = g.z;
            inT[bb][k4 + 3][ii] = g.w;
        }
        if (tid < 32) {
            int bb = tid >> 2, m4 = (tid & 3) * 4;
            *(float4*)&vl[bb * OU + m4] =
                *(const float4*)&v[((size_t)(bb0 + bb) * OC + o) * OU + m4];
        }
        __syncthreads();

#pragma unroll
        for (int bb = 0; bb < D_BCH; ++bb) {
            float x[IK];
#pragma unroll
            for (int k = 0; k < IK; ++k) x[k] = inT[bb][k][i_loc];
#pragma unroll
            for (int j = 0; j < 8; ++j) {
                float d = w[j][0]*x[0] + w[j][1]*x[1] + w[j][2]*x[2] + w[j][3]*x[3]
                        + w[j][4]*x[4] + w[j][5]*x[5] + w[j][6]*x[6] + w[j][7]*x[7];
                acc += d * vl[bb * OU + ug * 8 + j];
            }
        }
    }
    atomicAdd(&blog[(size_t)i * OC + o], acc * (1.0f / NB));
}

extern "C" void kernel_launch(void* const* d_in, const int* in_sizes, int n_in,
                              void* d_out, int out_size, void* d_ws, size_t ws_size,
                              hipStream_t stream) {
    const float* inp = (const float*)d_in[0];   // [256][1152][8]
    const float* W   = (const float*)d_in[1];   // [1152][10][16][8]
    float* vout = (float*)d_out;                // [256][10][16]

    float* blog = (float*)d_ws;                 // [1152][10]
    float* s    = blog + IC * OC;               // [256][10][16]

    hipMemsetAsync(d_ws, 0, (size_t)(IC * OC + NB * OC * OU) * sizeof(float), stream);

    for (int t = 0; t < 3; ++t) {
        spass_kernel<<<dim3(OC, 2, S_ISPLIT), dim3(256), 0, stream>>>(inp, W, blog, s);
        squash_kernel<<<dim3(NB * OC * OU / 256), dim3(256), 0, stream>>>(s, vout);
        if (t < 2)   // final-iteration b update is dead code in the reference
            delta_kernel<<<dim3(OC, IC / 128, D_BSPLIT), dim3(256), 0, stream>>>(inp, W, vout, blog);
    }
}

// Round 3
// 203.216 us; speedup vs baseline: 2.5381x; 2.5381x over previous
//
#include <hip/hip_runtime.h>
#include <math.h>

#define NB 256     // batch
#define IC 1152    // input capsules
#define OC 10      // output capsules
#define OU 16      // output units
#define IK 8       // input units
#define KTOT (IC * IK)        // 9216 = GEMM K for s-pass
#define NTOT (OC * OU)        // 160  = GEMM N
#define S_KS 128              // s-pass K-splits
#define S_KC (KTOT / S_KS)    // 72 (i,k) per block

// ---- Wc kernel: fused softmax + layout transform -------------------------
// Wc[(i*8+k)*160 + (o*16+u)] = softmax(blog[i,:])[o] * W[i,o,u,k]
__global__ __launch_bounds__(256) void wc_kernel(
    const float* __restrict__ W, const float* __restrict__ blog,
    float* __restrict__ wc)
{
    const int i   = blockIdx.x;
    const int tid = threadIdx.x;
    __shared__ float wrow[1280];
    __shared__ float c[OC];

#pragma unroll
    for (int jj = 0; jj < 5; ++jj)
        wrow[jj * 256 + tid] = W[(size_t)i * 1280 + jj * 256 + tid];

    if (tid < OC) {
        const float* br = &blog[(size_t)i * OC];
        float x[OC], m = -1e30f;
#pragma unroll
        for (int o = 0; o < OC; ++o) { x[o] = br[o]; m = fmaxf(m, x[o]); }
        float sum = 0.f;
#pragma unroll
        for (int o = 0; o < OC; ++o) sum += expf(x[o] - m);
        c[tid] = expf(x[tid] - m) / sum;
    }
    __syncthreads();

#pragma unroll
    for (int jj = 0; jj < 5; ++jj) {
        int t = jj * 256 + tid;
        int k = t / NTOT;             // 0..7
        int n = t - k * NTOT;         // 0..159
        wc[(size_t)i * 1280 + t] = c[n >> 4] * wrow[n * 8 + k];
    }
}

// ---- s-pass GEMM: part[ks][b][n] = sum_{k in chunk} inp[b][k] * Wc[k][n] --
// grid (4 M-tiles, 128 K-splits), 256 thr. Thread tile: 8 b x 5 n.
__global__ __launch_bounds__(256) void spass_kernel(
    const float* __restrict__ inp,   // [256][9216]
    const float* __restrict__ wc,    // [9216][160]
    float* __restrict__ part)        // [S_KS][256][160]
{
    const int mt  = blockIdx.x;      // b-tile
    const int ks  = blockIdx.y;      // k-split
    const int tid = threadIdx.x;
    const int mg  = tid >> 5;        // 0..7 -> b = mt*64 + mg*8 + r
    const int ln  = tid & 31;        // n = ln + 32*j
    const int b0  = mt * 64;
    const int k0  = ks * S_KC;

    __shared__ float A[64][76];      // [b-local][k-local], pad 76 (19.5 KB)

    // stage inp tile: 64 rows x 72 floats (18 float4/row), coalesced
#pragma unroll
    for (int jj = 0; jj < 5; ++jj) {
        int q = jj * 256 + tid;
        if (q < 64 * 18) {
            int b = q / 18, f = q - b * 18;
            float4 g = *(const float4*)&inp[(size_t)(b0 + b) * KTOT + k0 + f * 4];
            *(float4*)&A[b][f * 4] = g;
        }
    }
    __syncthreads();

    float acc[8][5];
#pragma unroll
    for (int r = 0; r < 8; ++r)
#pragma unroll
        for (int j = 0; j < 5; ++j) acc[r][j] = 0.f;

    const float* wcp = wc + (size_t)k0 * NTOT + ln;

    for (int k = 0; k < S_KC; k += 4) {
        float bv[4][5];
#pragma unroll
        for (int kk = 0; kk < 4; ++kk)
#pragma unroll
            for (int j = 0; j < 5; ++j)
                bv[kk][j] = wcp[(size_t)(k + kk) * NTOT + 32 * j];
#pragma unroll
        for (int r = 0; r < 8; ++r) {
            float4 a = *(const float4*)&A[mg * 8 + r][k];   // broadcast read
#pragma unroll
            for (int j = 0; j < 5; ++j) {
                acc[r][j] += a.x * bv[0][j];
                acc[r][j] += a.y * bv[1][j];
                acc[r][j] += a.z * bv[2][j];
                acc[r][j] += a.w * bv[3][j];
            }
        }
    }

    float* pp = part + ((size_t)ks * NB + b0) * NTOT;
#pragma unroll
    for (int r = 0; r < 8; ++r)
#pragma unroll
        for (int j = 0; j < 5; ++j)
            pp[(size_t)(mg * 8 + r) * NTOT + ln + 32 * j] = acc[r][j];
}

// ---- reduce partials + squash -> v ---------------------------------------
__global__ __launch_bounds__(256) void reduce_squash_kernel(
    const float* __restrict__ part, float* __restrict__ vout)
{
    const int e = blockIdx.x * 256 + threadIdx.x;   // < 40960
    float a[8];
#pragma unroll
    for (int jj = 0; jj < 8; ++jj) a[jj] = 0.f;
    for (int ks = 0; ks < S_KS; ks += 8) {
#pragma unroll
        for (int jj = 0; jj < 8; ++jj)
            a[jj] += part[(size_t)(ks + jj) * (NB * NTOT) + e];
    }
    float s = ((a[0] + a[1]) + (a[2] + a[3])) + ((a[4] + a[5]) + (a[6] + a[7]));
    float sq = s * s;
    sq += __shfl_xor(sq, 1);
    sq += __shfl_xor(sq, 2);
    sq += __shfl_xor(sq, 4);
    sq += __shfl_xor(sq, 8);
    vout[e] = s * (sq / ((1.f + sq) * sqrtf(sq + 1e-9f)));
}

// ---- delta GEMM + fused W-contraction ------------------------------------
// G[(i,k)][(o,u)] = sum_b inp[b][(i,k)] * v[b][(o,u)]  (per b-split of 64)
// blog[i,o] += 1/NB * sum_{u,k} W[i,o,u,k] * G[(i,k)][(o,u)]
// grid (144 m-tiles, 4 b-splits), 256 thr. Thread tile: 8 m (=1 i) x 5 n.
__global__ __launch_bounds__(256) void delta_kernel(
    const float* __restrict__ inp,   // [256][9216]
    const float* __restrict__ W,     // [1152][10][16][8]
    const float* __restrict__ v,     // [256][160]
    float* __restrict__ blog)        // [1152][10] accum
{
    const int mt  = blockIdx.x;      // m-tile: i = mt*8 + mg
    const int bs  = blockIdx.y;      // b-split
    const int tid = threadIdx.x;
    const int mg  = tid >> 5;
    const int ln  = tid & 31;
    const int m0  = mt * 64;
    const int b0  = bs * 64;

    __shared__ float A[64][68];      // [b-local][m-local], pad 68 (17.4 KB)

#pragma unroll
    for (int jj = 0; jj < 4; ++jj) {
        int q = jj * 256 + tid;
        int b = q >> 4, f = q & 15;
        float4 g = *(const float4*)&inp[(size_t)(b0 + b) * KTOT + m0 + f * 4];
        *(float4*)&A[b][f * 4] = g;
    }
    __syncthreads();

    float acc[8][5];
#pragma unroll
    for (int r = 0; r < 8; ++r)
#pragma unroll
        for (int j = 0; j < 5; ++j) acc[r][j] = 0.f;

    const float* vp = v + (size_t)b0 * NTOT + ln;

    for (int b = 0; b < 64; b += 4) {
        float bv[4][5];
#pragma unroll
        for (int kk = 0; kk < 4; ++kk)
#pragma unroll
            for (int j = 0; j < 5; ++j)
                bv[kk][j] = vp[(size_t)(b + kk) * NTOT + 32 * j];
#pragma unroll
        for (int kk = 0; kk < 4; ++kk) {
            float4 a0 = *(const float4*)&A[b + kk][mg * 8];      // broadcast
            float4 a1 = *(const float4*)&A[b + kk][mg * 8 + 4];
#pragma unroll
            for (int j = 0; j < 5; ++j) {
                acc[0][j] += a0.x * bv[kk][j];
                acc[1][j] += a0.y * bv[kk][j];
                acc[2][j] += a0.z * bv[kk][j];
                acc[3][j] += a0.w * bv[kk][j];
                acc[4][j] += a1.x * bv[kk][j];
                acc[5][j] += a1.y * bv[kk][j];
                acc[6][j] += a1.z * bv[kk][j];
                acc[7][j] += a1.w * bv[kk][j];
            }
        }
    }

    // epilogue: p[j] = sum_k W[i][o][u][k] * acc[k][j], reduce over 16 u-lanes
    const int i = mt * 8 + mg;
    float p[5];
#pragma unroll
    for (int j = 0; j < 5; ++j) {
        int n = ln + 32 * j;
        const float* wr = W + ((size_t)i * OC + (n >> 4)) * (OU * IK) + (n & 15) * IK;
        float4 w0 = *(const float4*)wr;
        float4 w1 = *(const float4*)(wr + 4);
        p[j] = w0.x * acc[0][j] + w0.y * acc[1][j] + w0.z * acc[2][j] + w0.w * acc[3][j]
             + w1.x * acc[4][j] + w1.y * acc[5][j] + w1.z * acc[6][j] + w1.w * acc[7][j];
    }
#pragma unroll
    for (int j = 0; j < 5; ++j) {
        p[j] += __shfl_xor(p[j], 1);
        p[j] += __shfl_xor(p[j], 2);
        p[j] += __shfl_xor(p[j], 4);
        p[j] += __shfl_xor(p[j], 8);
    }
    if ((tid & 15) == 0) {
#pragma unroll
        for (int j = 0; j < 5; ++j) {
            int o = (ln + 32 * j) >> 4;
            atomicAdd(&blog[(size_t)i * OC + o], p[j] * (1.0f / NB));
        }
    }
}

extern "C" void kernel_launch(void* const* d_in, const int* in_sizes, int n_in,
                              void* d_out, int out_size, void* d_ws, size_t ws_size,
                              hipStream_t stream) {
    const float* inp = (const float*)d_in[0];   // [256][1152][8]
    const float* W   = (const float*)d_in[1];   // [1152][10][16][8]
    float* vout = (float*)d_out;                // [256][10][16]

    float* blog = (float*)d_ws;                       // 11520
    float* wcb  = blog + IC * OC;                     // 1,474,560
    float* part = wcb + (size_t)KTOT * NTOT;          // 5,242,880  (~27 MB total)

    hipMemsetAsync(blog, 0, IC * OC * sizeof(float), stream);

    for (int t = 0; t < 3; ++t) {
        wc_kernel<<<dim3(IC), dim3(256), 0, stream>>>(W, blog, wcb);
        spass_kernel<<<dim3(4, S_KS), dim3(256), 0, stream>>>(inp, wcb, part);
        reduce_squash_kernel<<<dim3(NB * NTOT / 256), dim3(256), 0, stream>>>(part, vout);
        if (t < 2)   // final-iteration b update is dead code in the reference
            delta_kernel<<<dim3(IC / 8, 4), dim3(256), 0, stream>>>(inp, W, vout, blog);
    }
}